// Round 8
// baseline (144.219 us; speedup 1.0000x reference)
//
#include <hip/hip_runtime.h>
#include <math.h>

#define F0 136
#define F1 68
#define F2 6
#define KP 160   // K padded to 5*32
#define NP 80    // N padded to 5*16

typedef __attribute__((ext_vector_type(8))) short short8v;
typedef __attribute__((ext_vector_type(4))) float f32x4;

__device__ inline float bf2f(unsigned short u) {
    union { unsigned int i; float f; } v; v.i = ((unsigned int)u) << 16; return v.f;
}
__device__ inline unsigned short f2bf(float f) {
    union { float f; unsigned int i; } v; v.f = f;
    unsigned int r = v.i + 0x7FFFu + ((v.i >> 16) & 1u);  // round-nearest-even
    return (unsigned short)(r >> 16);
}

// ================= in-degree histogram over dst =================
__global__ void k_hist(const int* __restrict__ dst, int* __restrict__ counts, int E) {
    int e = blockIdx.x * blockDim.x + threadIdx.x;
    if (e < E) atomicAdd(&counts[dst[e]], 1);
}

// ===== fused small prep: W1->bf16 col-major padded  +  graph segments =====
__global__ void k_misc(const float* __restrict__ W1, unsigned short* __restrict__ Wb,
                       const int* __restrict__ batch, int* __restrict__ gs, int N, int G) {
    int i = blockIdx.x * blockDim.x + threadIdx.x;
    if (i < NP * KP) {
        int c = i / KP, k = i - c * KP;
        float v = (c < F1 && k < F0) ? W1[k * F1 + c] : 0.0f;
        Wb[c * KP + k] = f2bf(v);
    }
    if (i < N) {
        int bi = batch[i];
        int bp = (i == 0) ? -1 : batch[i - 1];
        for (int g = bp + 1; g <= bi; g++) gs[g] = i;
        if (i == N - 1) {
            for (int g = bi + 1; g <= G; g++) gs[g] = N;
        }
    }
}

// ===== alloc: block-local scan + atomic block offset (ranges unordered) ====
// also emits dinv. One launch replaces scanA/B/C.
__global__ __launch_bounds__(256) void k_alloc(const int* __restrict__ counts,
                                               int* __restrict__ row_start,
                                               int* __restrict__ cursor,
                                               float* __restrict__ dinv,
                                               int* __restrict__ total, int N) {
    __shared__ int s[256];
    __shared__ int sbase;
    int t = threadIdx.x;
    int base = blockIdx.x * 1024 + t * 4;
    int v[4], sum = 0;
#pragma unroll
    for (int u = 0; u < 4; u++) {
        int idx = base + u;
        v[u] = (idx < N) ? counts[idx] : 0;
        if (idx < N) dinv[idx] = rsqrtf((float)v[u] + 1.0f);  // self loop
        sum += v[u];
    }
    s[t] = sum;
    __syncthreads();
    for (int off = 1; off < 256; off <<= 1) {
        int y = (t >= off) ? s[t - off] : 0;
        __syncthreads();
        s[t] += y;
        __syncthreads();
    }
    if (t == 255) sbase = atomicAdd(total, s[255]);
    __syncthreads();
    int threadExcl = sbase + s[t] - sum;
    int run = 0;
#pragma unroll
    for (int u = 0; u < 4; u++) {
        int idx = base + u;
        if (idx < N) { row_start[idx] = threadExcl + run; cursor[idx] = threadExcl + run; }
        run += v[u];
    }
}

// ================= scatter edges into CSR (by dst), src index only =========
__global__ void k_scatter(const int* __restrict__ src, const int* __restrict__ dst,
                          int* __restrict__ cursor, int* __restrict__ ssrc, int E) {
    int e = blockIdx.x * blockDim.x + threadIdx.x;
    if (e >= E) return;
    int s = src[e], d = dst[e];
    int pos = atomicAdd(&cursor[d], 1);
    ssrc[pos] = s;
}

// ========== lin1 via MFMA: h1' = (x @ W1) * dinv, bf16 out ==========
__global__ __launch_bounds__(256) void k_lin1(const float* __restrict__ x,
                                              const unsigned short* __restrict__ Wb,
                                              const float* __restrict__ dinv,
                                              unsigned short* __restrict__ h1b, int N) {
    int tid  = threadIdx.x;
    int lane = tid & 63;
    int w    = tid >> 6;
    int rl   = lane & 15;
    int kg   = lane >> 4;
    int base = blockIdx.x * 64 + w * 16;
    int node = base + rl;
    int nodeClamp = node < N ? node : (N - 1);

    f32x4 acc[5];
#pragma unroll
    for (int t = 0; t < 5; t++) acc[t] = (f32x4){0.f, 0.f, 0.f, 0.f};

#pragma unroll
    for (int kt = 0; kt < 5; kt++) {
        int k0 = kt * 32 + kg * 8;
        short8v a;
        if (k0 < F0) {
            const float* xr = x + (size_t)nodeClamp * F0 + k0;
            float4 lo = *(const float4*)xr;
            float4 hi = *(const float4*)(xr + 4);
            a[0] = (short)f2bf(lo.x); a[1] = (short)f2bf(lo.y);
            a[2] = (short)f2bf(lo.z); a[3] = (short)f2bf(lo.w);
            a[4] = (short)f2bf(hi.x); a[5] = (short)f2bf(hi.y);
            a[6] = (short)f2bf(hi.z); a[7] = (short)f2bf(hi.w);
        } else {
            a = (short8v){0, 0, 0, 0, 0, 0, 0, 0};
        }
#pragma unroll
        for (int nt = 0; nt < 5; nt++) {
            int col = nt * 16 + rl;
            short8v b = *(const short8v*)&Wb[col * KP + k0];
            acc[nt] = __builtin_amdgcn_mfma_f32_16x16x32_bf16(a, b, acc[nt], 0, 0, 0);
        }
    }

    int orow0 = base + kg * 4;
    float dv[4];
#pragma unroll
    for (int j = 0; j < 4; j++) {
        int nr = orow0 + j;
        dv[j] = (nr < N) ? dinv[nr] : 0.0f;
    }
#pragma unroll
    for (int nt = 0; nt < 5; nt++) {
        int col = nt * 16 + rl;
        if (col < F1) {
#pragma unroll
            for (int j = 0; j < 4; j++) {
                int nr = orow0 + j;
                if (nr < N) h1b[(size_t)nr * F1 + col] = f2bf(acc[nt][j] * dv[j]);
            }
        }
    }
}

// ===== fused: agg1 gather (bf16) + bias/relu + @W2, high-ILP adjacency =====
// one wave per node; coalesced index preload + readlane broadcast;
// one predicated 16-wide chunk issues all gathers before a single wait.
__global__ __launch_bounds__(256) void k_gather1_lin2(const unsigned short* __restrict__ h1b,
                                                      const float* __restrict__ dinv,
                                                      const int* __restrict__ row_start,
                                                      const int* __restrict__ counts,
                                                      const int* __restrict__ ssrc,
                                                      const float* __restrict__ b1,
                                                      const float* __restrict__ W2,
                                                      float* __restrict__ h2p, int N) {
    __shared__ float sw2[F1 * F2];
    __shared__ float sb1[F1];
    int tid = threadIdx.x;
    for (int i = tid; i < F1 * F2; i += 256) sw2[i] = W2[i];
    if (tid < F1) sb1[tid] = b1[tid];
    __syncthreads();

    int lane = tid & 63;
    int n = blockIdx.x * 4 + (tid >> 6);
    if (n >= N) return;

    bool hi = lane < (F1 - 64);
    int colhi = 64 + (lane & 3);

    const unsigned short* selfrow = h1b + (size_t)n * F1;
    float acc0 = bf2f(selfrow[lane]);
    float acc1 = hi ? bf2f(selfrow[colhi]) : 0.0f;

    int js = row_start[n];
    int deg = counts[n];

    for (int w0 = 0; w0 < deg; w0 += 64) {
        int rem = deg - w0; rem = rem > 64 ? 64 : rem;
        // one coalesced VMEM covers the whole adjacency window
        int idxv = (lane < rem) ? ssrc[js + w0 + lane] : 0;  // invalid lanes -> row 0 (L1-hot)
        for (int u0 = 0; u0 < rem; u0 += 16) {
            float a[16], b[16];
#pragma unroll
            for (int u = 0; u < 16; u++) {
                int s = __shfl(idxv, u0 + u, 64);
                const unsigned short* r = h1b + (size_t)s * F1;
                bool val = (u0 + u) < rem;
                float av = bf2f(r[lane]);
                float bv = bf2f(r[colhi]);
                a[u] = val ? av : 0.0f;
                b[u] = val ? bv : 0.0f;
            }
#pragma unroll
            for (int u = 0; u < 16; u++) acc0 += a[u];
            if (hi) {
#pragma unroll
                for (int u = 0; u < 16; u++) acc1 += b[u];
            }
        }
    }

    float d = dinv[n];
    float v0 = fmaf(acc0, d, sb1[lane]);                 v0 = v0 > 0.0f ? v0 : 0.0f;
    float v1 = hi ? fmaf(acc1, d, sb1[colhi]) : 0.0f;    v1 = v1 > 0.0f ? v1 : 0.0f;

    float p[F2];
#pragma unroll
    for (int c = 0; c < F2; c++)
        p[c] = v0 * sw2[lane * F2 + c] + v1 * sw2[colhi * F2 + c];

#pragma unroll
    for (int off = 1; off < 64; off <<= 1) {
#pragma unroll
        for (int c = 0; c < F2; c++) p[c] += __shfl_xor(p[c], off, 64);
    }
    if (lane == 0) {
#pragma unroll
        for (int c = 0; c < F2; c++) h2p[(size_t)n * F2 + c] = p[c] * d;
    }
}

// ================= gather2 + bias/relu + head -> ynode (NO atomics) ========
__global__ __launch_bounds__(256) void k_gather2(const float* __restrict__ h2p,
                                                 const float* __restrict__ dinv,
                                                 const int* __restrict__ row_start,
                                                 const int* __restrict__ counts,
                                                 const int* __restrict__ ssrc,
                                                 const float* __restrict__ b2,
                                                 const float* __restrict__ Wl,
                                                 const float* __restrict__ bl,
                                                 const float* __restrict__ Wl2,
                                                 const float* __restrict__ bl2,
                                                 float* __restrict__ ynode, int N) {
    int t = blockIdx.x * blockDim.x + threadIdx.x;
    int n = t >> 3;
    int l = t & 7;
    if (n >= N) return;

    float acc[F2] = {0, 0, 0, 0, 0, 0};
    if (l == 0) {  // self-loop term h2'[n]
        const float* sr = h2p + (size_t)n * F2;
        float2 p0 = *(const float2*)&sr[0];
        float2 p1 = *(const float2*)&sr[2];
        float2 p2 = *(const float2*)&sr[4];
        acc[0] = p0.x; acc[1] = p0.y;
        acc[2] = p1.x; acc[3] = p1.y;
        acc[4] = p2.x; acc[5] = p2.y;
    }

    int js = row_start[n];
    int je = js + counts[n];
    for (int j = js + l; j < je; j += 8) {
        int s = ssrc[j];
        const float* r = h2p + (size_t)s * F2;
        float2 p0 = *(const float2*)&r[0];
        float2 p1 = *(const float2*)&r[2];
        float2 p2 = *(const float2*)&r[4];
        acc[0] += p0.x; acc[1] += p0.y;
        acc[2] += p1.x; acc[3] += p1.y;
        acc[4] += p2.x; acc[5] += p2.y;
    }

#pragma unroll
    for (int off = 1; off < 8; off <<= 1) {
#pragma unroll
        for (int c = 0; c < F2; c++) acc[c] += __shfl_xor(acc[c], off, 8);
    }

    if (l == 0) {
        float d = dinv[n];
        float y = 0.0f;
#pragma unroll
        for (int c = 0; c < F2; c++) {
            float v = fmaf(acc[c], d, b2[c]);
            v = v > 0.0f ? v : 0.0f;
            float we = Wl[c * 3 + 0] * Wl2[0] + Wl[c * 3 + 1] * Wl2[1] + Wl[c * 3 + 2] * Wl2[2];
            y = fmaf(v, we, y);
        }
        float cnst = bl[0] * Wl2[0] + bl[1] * Wl2[1] + bl[2] * Wl2[2] + bl2[0];
        ynode[n] = y + cnst;
    }
}

// ================= pool: one block per graph, tree reduce + sigmoid ========
__global__ __launch_bounds__(256) void k_pool(const float* __restrict__ ynode,
                                              const int* __restrict__ gs,
                                              float* __restrict__ out, int G) {
    int g = blockIdx.x;
    int s0 = gs[g], e0 = gs[g + 1];
    int t = threadIdx.x;
    float a = 0.0f;
    for (int i = s0 + t; i < e0; i += 256) a += ynode[i];
#pragma unroll
    for (int off = 1; off < 64; off <<= 1) a += __shfl_xor(a, off, 64);
    __shared__ float sm[4];
    if ((t & 63) == 0) sm[t >> 6] = a;
    __syncthreads();
    if (t == 0) {
        float tot = sm[0] + sm[1] + sm[2] + sm[3];
        out[g] = 1.0f / (1.0f + expf(-tot));
    }
}

extern "C" void kernel_launch(void* const* d_in, const int* in_sizes, int n_in,
                              void* d_out, int out_size, void* d_ws, size_t ws_size,
                              hipStream_t stream) {
    const float* x     = (const float*)d_in[0];
    const int*   ei    = (const int*)d_in[1];
    const int*   batch = (const int*)d_in[2];
    const float* W1    = (const float*)d_in[3];
    const float* b1    = (const float*)d_in[4];
    const float* W2    = (const float*)d_in[5];
    const float* b2    = (const float*)d_in[6];
    const float* Wl    = (const float*)d_in[7];
    const float* bl    = (const float*)d_in[8];
    const float* Wl2   = (const float*)d_in[9];
    const float* bl2   = (const float*)d_in[10];
    float* out = (float*)d_out;

    int N = in_sizes[0] / F0;   // 50000
    int E = in_sizes[1] / 2;    // 512000
    int G = out_size;           // 512
    const int* src = ei;
    const int* dst = ei + E;

    char* ws = (char*)d_ws;
    size_t off = 0;
    auto alloc = [&](size_t bytes) {
        void* p = ws + off;
        off = (off + bytes + 255) & ~(size_t)255;
        return p;
    };
    int*   counts    = (int*)alloc((size_t)(N + 1) * 4);  // [N] = total counter
    int*   row_start = (int*)alloc((size_t)N * 4);
    int*   cursor    = (int*)alloc((size_t)N * 4);
    float* dinv      = (float*)alloc((size_t)N * 4);
    int*   ssrc      = (int*)alloc((size_t)E * 4);
    unsigned short* h1b = (unsigned short*)alloc((size_t)N * F1 * 2);
    float* h2p       = (float*)alloc((size_t)N * F2 * 4);
    float* ynode     = (float*)alloc((size_t)N * 4);
    int*   gs        = (int*)alloc((size_t)(G + 1) * 4);
    unsigned short* Wb = (unsigned short*)alloc((size_t)NP * KP * 2);

    const int B = 256;
    int nScanBlocks = (N + 1023) / 1024;   // 49

    hipMemsetAsync(counts, 0, (size_t)(N + 1) * 4, stream);
    k_hist<<<(E + B - 1) / B, B, 0, stream>>>(dst, counts, E);
    k_misc<<<(N + B - 1) / B, B, 0, stream>>>(W1, Wb, batch, gs, N, G);
    k_alloc<<<nScanBlocks, 256, 0, stream>>>(counts, row_start, cursor, dinv, counts + N, N);
    k_scatter<<<(E + B - 1) / B, B, 0, stream>>>(src, dst, cursor, ssrc, E);
    k_lin1<<<(N + 63) / 64, 256, 0, stream>>>(x, Wb, dinv, h1b, N);
    k_gather1_lin2<<<(N + 3) / 4, 256, 0, stream>>>(h1b, dinv, row_start, counts, ssrc, b1, W2, h2p, N);
    k_gather2<<<((N * 8) + B - 1) / B, B, 0, stream>>>(h2p, dinv, row_start, counts, ssrc,
                                                       b2, Wl, bl, Wl2, bl2, ynode, N);
    k_pool<<<G, 256, 0, stream>>>(ynode, gs, out, G);
}

// Round 9
// 134.196 us; speedup vs baseline: 1.0747x; 1.0747x over previous
//
#include <hip/hip_runtime.h>
#include <math.h>

#define F0 136
#define F1 68
#define F2 6
#define KP 160   // K padded to 5*32
#define NP 80    // N padded to 5*16

typedef __attribute__((ext_vector_type(8))) short short8v;
typedef __attribute__((ext_vector_type(4))) float f32x4;

__device__ inline float bf2f(unsigned short u) {
    union { unsigned int i; float f; } v; v.i = ((unsigned int)u) << 16; return v.f;
}
__device__ inline unsigned short f2bf(float f) {
    union { float f; unsigned int i; } v; v.f = f;
    unsigned int r = v.i + 0x7FFFu + ((v.i >> 16) & 1u);  // round-nearest-even
    return (unsigned short)(r >> 16);
}

// ================= in-degree histogram over dst =================
__global__ void k_hist(const int* __restrict__ dst, int* __restrict__ counts, int E) {
    int e = blockIdx.x * blockDim.x + threadIdx.x;
    if (e < E) atomicAdd(&counts[dst[e]], 1);
}

// ===== fused small prep: W1->bf16 col-major padded  +  graph segments =====
__global__ void k_misc(const float* __restrict__ W1, unsigned short* __restrict__ Wb,
                       const int* __restrict__ batch, int* __restrict__ gs, int N, int G) {
    int i = blockIdx.x * blockDim.x + threadIdx.x;
    if (i < NP * KP) {
        int c = i / KP, k = i - c * KP;
        float v = (c < F1 && k < F0) ? W1[k * F1 + c] : 0.0f;
        Wb[c * KP + k] = f2bf(v);
    }
    if (i < N) {
        int bi = batch[i];
        int bp = (i == 0) ? -1 : batch[i - 1];
        for (int g = bp + 1; g <= bi; g++) gs[g] = i;
        if (i == N - 1) {
            for (int g = bi + 1; g <= G; g++) gs[g] = N;
        }
    }
}

// ===== alloc: block-local scan + atomic block offset (ranges unordered) ====
__global__ __launch_bounds__(256) void k_alloc(const int* __restrict__ counts,
                                               int* __restrict__ row_start,
                                               int* __restrict__ cursor,
                                               float* __restrict__ dinv,
                                               int* __restrict__ total, int N) {
    __shared__ int s[256];
    __shared__ int sbase;
    int t = threadIdx.x;
    int base = blockIdx.x * 1024 + t * 4;
    int v[4], sum = 0;
#pragma unroll
    for (int u = 0; u < 4; u++) {
        int idx = base + u;
        v[u] = (idx < N) ? counts[idx] : 0;
        if (idx < N) dinv[idx] = rsqrtf((float)v[u] + 1.0f);  // self loop
        sum += v[u];
    }
    s[t] = sum;
    __syncthreads();
    for (int off = 1; off < 256; off <<= 1) {
        int y = (t >= off) ? s[t - off] : 0;
        __syncthreads();
        s[t] += y;
        __syncthreads();
    }
    if (t == 255) sbase = atomicAdd(total, s[255]);
    __syncthreads();
    int threadExcl = sbase + s[t] - sum;
    int run = 0;
#pragma unroll
    for (int u = 0; u < 4; u++) {
        int idx = base + u;
        if (idx < N) { row_start[idx] = threadExcl + run; cursor[idx] = threadExcl + run; }
        run += v[u];
    }
}

// ================= scatter edges into CSR (by dst), src index only =========
__global__ void k_scatter(const int* __restrict__ src, const int* __restrict__ dst,
                          int* __restrict__ cursor, int* __restrict__ ssrc, int E) {
    int e = blockIdx.x * blockDim.x + threadIdx.x;
    if (e >= E) return;
    int s = src[e], d = dst[e];
    int pos = atomicAdd(&cursor[d], 1);
    ssrc[pos] = s;
}

// ========== lin1 via MFMA: h1' = (x @ W1) * dinv, bf16, SPLIT layout =======
// main cols 0..63 -> h1a [N][64] (128B-aligned rows); cols 64..67 -> h1t [N][4]
__global__ __launch_bounds__(256) void k_lin1(const float* __restrict__ x,
                                              const unsigned short* __restrict__ Wb,
                                              const float* __restrict__ dinv,
                                              unsigned short* __restrict__ h1a,
                                              unsigned short* __restrict__ h1t, int N) {
    int tid  = threadIdx.x;
    int lane = tid & 63;
    int w    = tid >> 6;
    int rl   = lane & 15;
    int kg   = lane >> 4;
    int base = blockIdx.x * 64 + w * 16;
    int node = base + rl;
    int nodeClamp = node < N ? node : (N - 1);

    f32x4 acc[5];
#pragma unroll
    for (int t = 0; t < 5; t++) acc[t] = (f32x4){0.f, 0.f, 0.f, 0.f};

#pragma unroll
    for (int kt = 0; kt < 5; kt++) {
        int k0 = kt * 32 + kg * 8;
        short8v a;
        if (k0 < F0) {
            const float* xr = x + (size_t)nodeClamp * F0 + k0;
            float4 lo = *(const float4*)xr;
            float4 hi = *(const float4*)(xr + 4);
            a[0] = (short)f2bf(lo.x); a[1] = (short)f2bf(lo.y);
            a[2] = (short)f2bf(lo.z); a[3] = (short)f2bf(lo.w);
            a[4] = (short)f2bf(hi.x); a[5] = (short)f2bf(hi.y);
            a[6] = (short)f2bf(hi.z); a[7] = (short)f2bf(hi.w);
        } else {
            a = (short8v){0, 0, 0, 0, 0, 0, 0, 0};
        }
#pragma unroll
        for (int nt = 0; nt < 5; nt++) {
            int col = nt * 16 + rl;
            short8v b = *(const short8v*)&Wb[col * KP + k0];
            acc[nt] = __builtin_amdgcn_mfma_f32_16x16x32_bf16(a, b, acc[nt], 0, 0, 0);
        }
    }

    int orow0 = base + kg * 4;
    float dv[4];
#pragma unroll
    for (int j = 0; j < 4; j++) {
        int nr = orow0 + j;
        dv[j] = (nr < N) ? dinv[nr] : 0.0f;
    }
#pragma unroll
    for (int nt = 0; nt < 4; nt++) {   // cols 0..63 -> h1a
        int col = nt * 16 + rl;
#pragma unroll
        for (int j = 0; j < 4; j++) {
            int nr = orow0 + j;
            if (nr < N) h1a[(size_t)nr * 64 + col] = f2bf(acc[nt][j] * dv[j]);
        }
    }
    {   // cols 64..67 -> h1t
        int col = 64 + rl;
        if (col < F1) {
#pragma unroll
            for (int j = 0; j < 4; j++) {
                int nr = orow0 + j;
                if (nr < N) h1t[(size_t)nr * 4 + rl] = f2bf(acc[4][j] * dv[j]);
            }
        }
    }
}

// ===== fused: agg1 gather (split bf16) + bias/relu + @W2 -> h2p ============
// one wave per node. Coalesced 64-wide index preload + shfl broadcast.
// Main cols: 1 aligned VMEM instr per edge. Tail cols: 16 edges per instr,
// cross-lane reduced (strides 4..32). Lean registers (8-deep chunks).
__global__ __launch_bounds__(256) void k_gather1_lin2(const unsigned short* __restrict__ h1a,
                                                      const unsigned short* __restrict__ h1t,
                                                      const float* __restrict__ dinv,
                                                      const int* __restrict__ row_start,
                                                      const int* __restrict__ counts,
                                                      const int* __restrict__ ssrc,
                                                      const float* __restrict__ b1,
                                                      const float* __restrict__ W2,
                                                      float* __restrict__ h2p, int N) {
    __shared__ float sw2[F1 * F2];
    __shared__ float sb1[F1];
    int tid = threadIdx.x;
    for (int i = tid; i < F1 * F2; i += 256) sw2[i] = W2[i];
    if (tid < F1) sb1[tid] = b1[tid];
    __syncthreads();

    int lane = tid & 63;
    int n = blockIdx.x * 4 + (tid >> 6);
    if (n >= N) return;

    // self terms
    float acc0 = bf2f(h1a[(size_t)n * 64 + lane]);          // cols 0..63
    float acct = (lane < 4) ? bf2f(h1t[(size_t)n * 4 + lane]) : 0.0f;  // cols 64..67 partial

    int js = row_start[n];
    int deg = counts[n];

    for (int w0 = 0; w0 < deg; w0 += 64) {
        int wlen = deg - w0; wlen = wlen > 64 ? 64 : wlen;
        int li = lane < wlen ? lane : wlen - 1;
        int idxv = ssrc[js + w0 + li];          // one coalesced VMEM for whole window

        int u0 = 0;
        for (; u0 + 8 <= wlen; u0 += 8) {       // full 8-chunks: all gathers independent
            int s[8];
#pragma unroll
            for (int u = 0; u < 8; u++) s[u] = __shfl(idxv, u0 + u, 64);
            float a[8];
#pragma unroll
            for (int u = 0; u < 8; u++) a[u] = bf2f(h1a[(size_t)s[u] * 64 + lane]);
#pragma unroll
            for (int u = 0; u < 8; u++) acc0 += a[u];
        }
        int rem = wlen - u0;
        if (rem > 0) {                          // predicated 8-chunk tail
            int s[8];
#pragma unroll
            for (int u = 0; u < 8; u++) {
                int uu = (u < rem) ? (u0 + u) : u0;
                s[u] = __shfl(idxv, uu, 64);
            }
            float a[8];
#pragma unroll
            for (int u = 0; u < 8; u++) a[u] = bf2f(h1a[(size_t)s[u] * 64 + lane]);
#pragma unroll
            for (int u = 0; u < 8; u++) acc0 += (u < rem) ? a[u] : 0.0f;
        }

        // tail cols 64..67: 16 edges per instruction, lane -> (edge e0+(lane>>2), col lane&3)
        for (int e0 = 0; e0 < wlen; e0 += 16) {
            int ee = e0 + (lane >> 2);
            bool val = ee < wlen;
            int s = __shfl(idxv, val ? ee : 0, 64);
            float tv = bf2f(h1t[(size_t)s * 4 + (lane & 3)]);
            acct += val ? tv : 0.0f;
        }
    }

    // reduce tail partials across the 16 lane-groups sharing the same (lane&3)
#pragma unroll
    for (int off = 4; off < 64; off <<= 1) acct += __shfl_xor(acct, off, 64);

    bool hi = lane < (F1 - 64);
    int colhi = 64 + (lane & 3);

    float d = dinv[n];
    float v0 = fmaf(acc0, d, sb1[lane]);                 v0 = v0 > 0.0f ? v0 : 0.0f;
    float v1 = hi ? fmaf(acct, d, sb1[colhi]) : 0.0f;    v1 = v1 > 0.0f ? v1 : 0.0f;

    float p[F2];
#pragma unroll
    for (int c = 0; c < F2; c++)
        p[c] = v0 * sw2[lane * F2 + c] + v1 * sw2[colhi * F2 + c];

#pragma unroll
    for (int off = 1; off < 64; off <<= 1) {
#pragma unroll
        for (int c = 0; c < F2; c++) p[c] += __shfl_xor(p[c], off, 64);
    }
    if (lane == 0) {
#pragma unroll
        for (int c = 0; c < F2; c++) h2p[(size_t)n * F2 + c] = p[c] * d;
    }
}

// ================= gather2 + bias/relu + head -> ynode (NO atomics) ========
__global__ __launch_bounds__(256) void k_gather2(const float* __restrict__ h2p,
                                                 const float* __restrict__ dinv,
                                                 const int* __restrict__ row_start,
                                                 const int* __restrict__ counts,
                                                 const int* __restrict__ ssrc,
                                                 const float* __restrict__ b2,
                                                 const float* __restrict__ Wl,
                                                 const float* __restrict__ bl,
                                                 const float* __restrict__ Wl2,
                                                 const float* __restrict__ bl2,
                                                 float* __restrict__ ynode, int N) {
    int t = blockIdx.x * blockDim.x + threadIdx.x;
    int n = t >> 3;
    int l = t & 7;
    if (n >= N) return;

    float acc[F2] = {0, 0, 0, 0, 0, 0};
    if (l == 0) {  // self-loop term h2'[n]
        const float* sr = h2p + (size_t)n * F2;
        float2 p0 = *(const float2*)&sr[0];
        float2 p1 = *(const float2*)&sr[2];
        float2 p2 = *(const float2*)&sr[4];
        acc[0] = p0.x; acc[1] = p0.y;
        acc[2] = p1.x; acc[3] = p1.y;
        acc[4] = p2.x; acc[5] = p2.y;
    }

    int js = row_start[n];
    int je = js + counts[n];
    for (int j = js + l; j < je; j += 8) {
        int s = ssrc[j];
        const float* r = h2p + (size_t)s * F2;
        float2 p0 = *(const float2*)&r[0];
        float2 p1 = *(const float2*)&r[2];
        float2 p2 = *(const float2*)&r[4];
        acc[0] += p0.x; acc[1] += p0.y;
        acc[2] += p1.x; acc[3] += p1.y;
        acc[4] += p2.x; acc[5] += p2.y;
    }

#pragma unroll
    for (int off = 1; off < 8; off <<= 1) {
#pragma unroll
        for (int c = 0; c < F2; c++) acc[c] += __shfl_xor(acc[c], off, 8);
    }

    if (l == 0) {
        float d = dinv[n];
        float y = 0.0f;
#pragma unroll
        for (int c = 0; c < F2; c++) {
            float v = fmaf(acc[c], d, b2[c]);
            v = v > 0.0f ? v : 0.0f;
            float we = Wl[c * 3 + 0] * Wl2[0] + Wl[c * 3 + 1] * Wl2[1] + Wl[c * 3 + 2] * Wl2[2];
            y = fmaf(v, we, y);
        }
        float cnst = bl[0] * Wl2[0] + bl[1] * Wl2[1] + bl[2] * Wl2[2] + bl2[0];
        ynode[n] = y + cnst;
    }
}

// ================= pool: one block per graph, tree reduce + sigmoid ========
__global__ __launch_bounds__(256) void k_pool(const float* __restrict__ ynode,
                                              const int* __restrict__ gs,
                                              float* __restrict__ out, int G) {
    int g = blockIdx.x;
    int s0 = gs[g], e0 = gs[g + 1];
    int t = threadIdx.x;
    float a = 0.0f;
    for (int i = s0 + t; i < e0; i += 256) a += ynode[i];
#pragma unroll
    for (int off = 1; off < 64; off <<= 1) a += __shfl_xor(a, off, 64);
    __shared__ float sm[4];
    if ((t & 63) == 0) sm[t >> 6] = a;
    __syncthreads();
    if (t == 0) {
        float tot = sm[0] + sm[1] + sm[2] + sm[3];
        out[g] = 1.0f / (1.0f + expf(-tot));
    }
}

extern "C" void kernel_launch(void* const* d_in, const int* in_sizes, int n_in,
                              void* d_out, int out_size, void* d_ws, size_t ws_size,
                              hipStream_t stream) {
    const float* x     = (const float*)d_in[0];
    const int*   ei    = (const int*)d_in[1];
    const int*   batch = (const int*)d_in[2];
    const float* W1    = (const float*)d_in[3];
    const float* b1    = (const float*)d_in[4];
    const float* W2    = (const float*)d_in[5];
    const float* b2    = (const float*)d_in[6];
    const float* Wl    = (const float*)d_in[7];
    const float* bl    = (const float*)d_in[8];
    const float* Wl2   = (const float*)d_in[9];
    const float* bl2   = (const float*)d_in[10];
    float* out = (float*)d_out;

    int N = in_sizes[0] / F0;   // 50000
    int E = in_sizes[1] / 2;    // 512000
    int G = out_size;           // 512
    const int* src = ei;
    const int* dst = ei + E;

    char* ws = (char*)d_ws;
    size_t off = 0;
    auto alloc = [&](size_t bytes) {
        void* p = ws + off;
        off = (off + bytes + 255) & ~(size_t)255;
        return p;
    };
    int*   counts    = (int*)alloc((size_t)(N + 1) * 4);  // [N] = total counter
    int*   row_start = (int*)alloc((size_t)N * 4);
    int*   cursor    = (int*)alloc((size_t)N * 4);
    float* dinv      = (float*)alloc((size_t)N * 4);
    int*   ssrc      = (int*)alloc((size_t)E * 4);
    unsigned short* h1a = (unsigned short*)alloc((size_t)N * 64 * 2);  // 128B rows
    unsigned short* h1t = (unsigned short*)alloc((size_t)N * 4 * 2);   // tail cols
    float* h2p       = (float*)alloc((size_t)N * F2 * 4);
    float* ynode     = (float*)alloc((size_t)N * 4);
    int*   gs        = (int*)alloc((size_t)(G + 1) * 4);
    unsigned short* Wb = (unsigned short*)alloc((size_t)NP * KP * 2);

    const int B = 256;
    int nScanBlocks = (N + 1023) / 1024;   // 49

    hipMemsetAsync(counts, 0, (size_t)(N + 1) * 4, stream);
    k_hist<<<(E + B - 1) / B, B, 0, stream>>>(dst, counts, E);
    k_misc<<<(N + B - 1) / B, B, 0, stream>>>(W1, Wb, batch, gs, N, G);
    k_alloc<<<nScanBlocks, 256, 0, stream>>>(counts, row_start, cursor, dinv, counts + N, N);
    k_scatter<<<(E + B - 1) / B, B, 0, stream>>>(src, dst, cursor, ssrc, E);
    k_lin1<<<(N + 63) / 64, 256, 0, stream>>>(x, Wb, dinv, h1a, h1t, N);
    k_gather1_lin2<<<(N + 3) / 4, 256, 0, stream>>>(h1a, h1t, dinv, row_start, counts, ssrc,
                                                    b1, W2, h2p, N);
    k_gather2<<<((N * 8) + B - 1) / B, B, 0, stream>>>(h2p, dinv, row_start, counts, ssrc,
                                                       b2, Wl, bl, Wl2, bl2, ynode, N);
    k_pool<<<G, 256, 0, stream>>>(ynode, gs, out, G);
}